// Round 4
// baseline (145.510 us; speedup 1.0000x reference)
//
#include <hip/hip_runtime.h>
#include <hip/hip_cooperative_groups.h>

namespace cg = cooperative_groups;

#define NN   256   // Preisach mesh size
#define TT   16    // outputs (steps) per chunk
#define GMAX 256   // grid size == max chunks

__device__ __forceinline__ float softplus_f(float x) {
    if (x > 20.0f) return x;
    return log1pf(expf(x));
}

// Single cooperative kernel: phase1 (pref rows + chunk tables) -> grid sync ->
// phase2 (exclusive prefix-max of last-flip tables over chunks) -> grid sync ->
// phase3 (per-chunk carry-in + barrier-free 16-step incremental walk).
__global__ void __launch_bounds__(256)
k_all(const float* __restrict__ h_g, const float* __restrict__ raw,
      float* __restrict__ out, int M, int G,
      float* __restrict__ PrefT, float* __restrict__ RowTot,
      int* __restrict__ steps_g, unsigned int* __restrict__ UDt,
      unsigned int* __restrict__ UDpre)
{
    cg::grid_group grid = cg::this_grid();
    __shared__ float s[NN];
    __shared__ float xs[NN];
    __shared__ float hh[TT + 1];
    __shared__ int   dd[TT + 1];
    __shared__ int   su[GMAX], sd[GMAX];
    __shared__ int   Dv[NN];
    __shared__ float red[4 * 18];
    __shared__ float tot[18];
    __shared__ int   rec_s[TT + 1];

    int b = blockIdx.x, tid = threadIdx.x;

    // ---- Phase 1a: prefix sums of dens row b (transposed store) ----
    xs[tid] = (float)((double)tid / 255.0);   // np.linspace(0,1,256), f64->f32
    {
        float v = 0.0f;
        if (tid <= b) v = softplus_f(raw[b * (b + 1) / 2 + tid]);
        s[tid] = v;
        __syncthreads();
        for (int off = 1; off < NN; off <<= 1) {   // Hillis-Steele inclusive
            float add = (tid >= off) ? s[tid - off] : 0.0f;
            __syncthreads();
            s[tid] += add;
            __syncthreads();
        }
        PrefT[(tid + 1) * NN + b] = s[tid];
        if (tid == 0)      PrefT[b] = 0.0f;
        if (tid == NN - 1) RowTot[b] = s[tid];
    }
    // ---- Phase 1b: chunk b -> packed step records + last-flip table ----
    if (b < G) {
        int t0 = b * TT;
        int Tb = min(TT, M - t0);
        if (tid < Tb) {
            int tau = t0 + 1 + tid;
            float cur  = (h_g[tau - 1] + 1.0f) * 0.5f;
            float prev = (tau == 1) ? 1.0f : (h_g[tau - 2] + 1.0f) * 0.5f;
            int d = (cur > prev) ? 2 : ((cur < prev) ? 0 : 1);
            int lo = 0, hi = NN;                 // ih = #{x < cur}
            while (lo < hi) { int m = (lo + hi) >> 1; if (xs[m] < cur) lo = m + 1; else hi = m; }
            int ih = lo;
            lo = 0; hi = NN;                     // jh = #{x <= cur}
            while (lo < hi) { int m = (lo + hi) >> 1; if (xs[m] <= cur) lo = m + 1; else hi = m; }
            int jh = lo;
            hh[1 + tid] = cur;
            dd[1 + tid] = d - 1;
            steps_g[tau] = d | (ih << 2) | (jh << 11);
        }
        __syncthreads();
        float xi = xs[tid];
        int Ue = 0, De = 0;                      // absolute (tau+1), 0 = none
        for (int k = 1; k <= Tb; ++k) {
            float hv = hh[k]; int d = dd[k];
            if (d > 0 && hv > xi) Ue = t0 + k + 1;
            if (d < 0 && hv < xi) De = t0 + k + 1;
        }
        UDt[tid * GMAX + b] = (unsigned)Ue | ((unsigned)De << 16);
    }
    grid.sync();

    // ---- Phase 2: threshold b — exclusive prefix-max over chunk axis ----
    {
        unsigned v = (tid < G) ? UDt[b * GMAX + tid] : 0u;
        su[tid] = (int)(v & 0xFFFFu);
        sd[tid] = (int)(v >> 16);
        __syncthreads();
        for (int off = 1; off < GMAX; off <<= 1) {   // inclusive max-scan
            int au = (tid >= off) ? su[tid - off] : 0;
            int ad = (tid >= off) ? sd[tid - off] : 0;
            __syncthreads();
            if (au > su[tid]) su[tid] = au;
            if (ad > sd[tid]) sd[tid] = ad;
            __syncthreads();
        }
        if (tid < G) {
            float hsM = (h_g[M - 1] + 1.0f) * 0.5f;  // hs[M]; step 0 has h=1.0
            int u0 = (hsM < 1.0f && b < NN - 1) ? 1 : 0;
            int Ue = (tid > 0) ? su[tid - 1] : 0;    // exclusive
            int De = (tid > 0) ? sd[tid - 1] : 0;
            if (u0 > Ue) Ue = u0;
            UDpre[tid * NN + b] = (unsigned)Ue | ((unsigned)De << 16);
        }
    }
    grid.sync();

    if (b >= G) return;
    // ---- Phase 3: chunk b — carry-in + barrier-free incremental walk ----
    int t0 = b * TT;
    int Tb = min(TT, M - t0);
    if (tid < TT) rec_s[1 + tid] = (tid < Tb) ? steps_g[t0 + 1 + tid] : 0;
    float RT = RowTot[tid];
    unsigned v = UDpre[b * NN + tid];            // one coalesced dword
    int Ue = (int)(v & 0xFFFFu);
    Dv[tid] = (int)(v >> 16);
    __syncthreads();

    float pk[TT + 1];                            // prefetch PrefT rows per step
    #pragma unroll
    for (int k = 1; k <= TT; ++k) {
        int jh = (rec_s[k] >> 11) & 0x1FF;
        pk[k] = PrefT[jh * NN + tid];
    }

    int lo = 0, hi = NN;                         // c = #{j : De_j < Ue_i}
    while (lo < hi) { int m = (lo + hi) >> 1; if (Dv[m] < Ue) lo = m + 1; else hi = m; }
    int c = min(lo, tid + 1);
    float w = 2.0f * PrefT[c * NN + tid] - RT;

    float vals[18];
    vals[0] = RT; vals[1] = w;
    int cc = c; float ww = w;
    #pragma unroll
    for (int k = 1; k <= TT; ++k) {              // per-thread walk, no barriers
        float dl = 0.0f;
        if (k <= Tb) {
            int rec = rec_s[k];
            int d = rec & 3;
            if (d == 2) {                        // up: rows i < ih -> +RowTot
                int ih = (rec >> 2) & 0x1FF;
                if (tid < ih) { dl = RT - ww; ww = RT; cc = tid + 1; }
            } else if (d == 0) {                 // down: truncate prefix to jh
                int jh = (rec >> 11) & 0x1FF;
                if (cc > jh) { float wn = 2.0f * pk[k] - RT; dl = wn - ww; ww = wn; cc = jh; }
            }
        }
        vals[1 + k] = dl;
    }

    #pragma unroll
    for (int q = 0; q < 18; ++q)                 // wave reduce all 18 quantities
        for (int off = 32; off; off >>= 1)
            vals[q] += __shfl_down(vals[q], off, 64);
    int lane = tid & 63, wv = tid >> 6;
    if (lane == 0) {
        #pragma unroll
        for (int q = 0; q < 18; ++q) red[wv * 18 + q] = vals[q];
    }
    __syncthreads();
    if (tid < 18) tot[tid] = red[tid] + red[18 + tid] + red[36 + tid] + red[54 + tid];
    __syncthreads();
    if (tid < TT) {                              // 16-lane shuffle prefix-scan
        float x = tot[2 + tid];
        #pragma unroll
        for (int off = 1; off < TT; off <<= 1) {
            float y = __shfl_up(x, off, 64);
            if (tid >= off) x += y;
        }
        if (tid < Tb) out[t0 + tid] = (tot[1] + x) * (1.0f / tot[0]);
    }
}

extern "C" void kernel_launch(void* const* d_in, const int* in_sizes, int n_in,
                              void* d_out, int out_size, void* d_ws, size_t ws_size,
                              hipStream_t stream) {
    const float* h   = (const float*)d_in[0];
    const float* raw = (const float*)d_in[1];
    float* out = (float*)d_out;
    int M = in_sizes[0];            // 4000
    int G = (M + TT - 1) / TT;      // 250 chunks (must be <= GMAX)

    char* ws = (char*)d_ws;
    size_t off = 0;
    auto take = [&](size_t bytes) { size_t cur = off; off = (off + bytes + 255) & ~(size_t)255; return cur; };
    float*        PrefT  = (float*)(ws + take((size_t)(NN + 1) * NN * 4));
    float*        RowTot = (float*)(ws + take((size_t)NN * 4));
    int*          steps  = (int*)(ws + take((size_t)(M + 1) * 4));
    unsigned int* UDt    = (unsigned int*)(ws + take((size_t)NN * GMAX * 4));
    unsigned int* UDpre  = (unsigned int*)(ws + take((size_t)GMAX * NN * 4));

    void* args[] = { (void*)&h, (void*)&raw, (void*)&out, (void*)&M, (void*)&G,
                     (void*)&PrefT, (void*)&RowTot, (void*)&steps,
                     (void*)&UDt, (void*)&UDpre };
    hipLaunchCooperativeKernel((const void*)k_all, dim3(GMAX), dim3(256),
                               args, 0, stream);
}

// Round 5
// 69.900 us; speedup vs baseline: 2.0817x; 2.0817x over previous
//
#include <hip/hip_runtime.h>

#define NN 256     // Preisach mesh size
#define TT 32      // outputs (steps) per chunk
// G = ceil(M/TT) = 125 chunks for M=4000

__device__ __forceinline__ float softplus_f(float x) {
    if (x > 20.0f) return x;
    return log1pf(expf(x));
}

// ---- kA: fused. Blocks [0,NN): prefix rows of dens (transposed store).
//          Blocks [NN, NN+G): chunk tables (packed step records + last-flip).
__global__ void __launch_bounds__(256)
kA(const float* __restrict__ h_g, const float* __restrict__ raw, int M, int G,
   float* __restrict__ PrefT, float* __restrict__ RowTot,
   int* __restrict__ steps_g, unsigned int* __restrict__ UDt)
{
    int b = blockIdx.x, tid = threadIdx.x;
    if (b < NN) {
        // per-row prefix sums of dens = softplus(raw) on lower triangle
        __shared__ float s[NN];
        float v = 0.0f;
        if (tid <= b) v = softplus_f(raw[b * (b + 1) / 2 + tid]);
        s[tid] = v;
        __syncthreads();
        for (int off = 1; off < NN; off <<= 1) {   // Hillis-Steele inclusive
            float add = (tid >= off) ? s[tid - off] : 0.0f;
            __syncthreads();
            s[tid] += add;
            __syncthreads();
        }
        PrefT[(tid + 1) * NN + b] = s[tid];        // PrefT[k][i], k=0..256
        if (tid == 0)      PrefT[b] = 0.0f;
        if (tid == NN - 1) RowTot[b] = s[tid];
    } else {
        // chunk c: steps tau in [t0+1, t0+Tb]
        __shared__ float xs[NN];
        __shared__ float hh[TT + 1];
        __shared__ int   dd[TT + 1];
        int c  = b - NN;
        int t0 = c * TT;
        int Tb = min(TT, M - t0);
        xs[tid] = (float)((double)tid / 255.0);    // np.linspace(0,1,256) f64->f32
        __syncthreads();
        if (tid < Tb) {
            int tau = t0 + 1 + tid;
            float cur  = (h_g[tau - 1] + 1.0f) * 0.5f;
            float prev = (tau == 1) ? 1.0f : (h_g[tau - 2] + 1.0f) * 0.5f;
            int d = (cur > prev) ? 2 : ((cur < prev) ? 0 : 1);
            int lo = 0, hi = NN;                   // ih = #{x < cur}
            while (lo < hi) { int m = (lo + hi) >> 1; if (xs[m] < cur) lo = m + 1; else hi = m; }
            int ih = lo;
            lo = 0; hi = NN;                       // jh = #{x <= cur}
            while (lo < hi) { int m = (lo + hi) >> 1; if (xs[m] <= cur) lo = m + 1; else hi = m; }
            int jh = lo;
            hh[1 + tid] = cur;
            dd[1 + tid] = d - 1;
            steps_g[tau] = d | (ih << 2) | (jh << 11);
        }
        __syncthreads();
        float xi = xs[tid];
        int Ue = 0, De = 0;                        // absolute tau+1, 0 = none
        for (int k = 1; k <= Tb; ++k) {
            float hv = hh[k]; int d = dd[k];
            if (d > 0 && hv > xi) Ue = t0 + k + 1;
            if (d < 0 && hv < xi) De = t0 + k + 1;
        }
        UDt[c * NN + tid] = (unsigned)Ue | ((unsigned)De << 16);  // chunk-major
    }
}

// ---- kB: per-chunk carry-in (ILP-16 max-scan over prior chunks) + walk ----
__global__ void __launch_bounds__(256)
kB(const float* __restrict__ h_g, const int* __restrict__ steps_g,
   const unsigned int* __restrict__ UDt,
   const float* __restrict__ PrefT, const float* __restrict__ RowTot,
   float* __restrict__ out, int M)
{
    __shared__ int   rec_s[TT + 1];
    __shared__ int   Dv[NN];
    __shared__ float red[4 * (TT + 2)];
    __shared__ float tot[TT + 2];
    int b = blockIdx.x, tid = threadIdx.x;
    int t0 = b * TT;
    int Tb = min(TT, M - t0);

    if (tid < TT) rec_s[1 + tid] = (tid < Tb) ? steps_g[t0 + 1 + tid] : 0;
    float RT = RowTot[tid];

    // carry-in: tau=0 step (h = 1.0) then max over previous chunk tables
    float hsM = (h_g[M - 1] + 1.0f) * 0.5f;        // hs[M] (roll wrap)
    unsigned uM = (hsM < 1.0f && tid < NN - 1) ? 1u : 0u;
    unsigned dM = 0u;
    const unsigned int* p = UDt + tid;
    int k = 0;
    for (; k + 16 <= b; k += 16) {                 // 16 loads in flight
        unsigned vv[16];
        #pragma unroll
        for (int u = 0; u < 16; ++u) vv[u] = p[(k + u) * NN];
        #pragma unroll
        for (int u = 0; u < 16; ++u) {
            unsigned ue = vv[u] & 0xFFFFu, de = vv[u] >> 16;
            if (ue > uM) uM = ue;
            if (de > dM) dM = de;
        }
    }
    for (; k < b; ++k) {
        unsigned v = p[k * NN];
        unsigned ue = v & 0xFFFFu, de = v >> 16;
        if (ue > uM) uM = ue;
        if (de > dM) dM = de;
    }
    int Ue = (int)uM;
    Dv[tid] = (int)dM;
    __syncthreads();

    // prefetch PrefT rows for each step's jh (coalesced)
    float pk[TT + 1];
    #pragma unroll
    for (int kk = 1; kk <= TT; ++kk) {
        int jh = (rec_s[kk] >> 11) & 0x1FF;
        pk[kk] = PrefT[jh * NN + tid];
    }

    // c = #{j : De_j < Ue_i} (Dv non-decreasing), clamp to triangle
    int lo = 0, hi = NN;
    while (lo < hi) { int m = (lo + hi) >> 1; if (Dv[m] < Ue) lo = m + 1; else hi = m; }
    int c = min(lo, tid + 1);
    float w = 2.0f * PrefT[c * NN + tid] - RT;

    // barrier-free walk: per-thread deltas per step
    float vals[TT + 2];
    vals[0] = RT; vals[1] = w;
    int cc = c; float ww = w;
    #pragma unroll
    for (int kk = 1; kk <= TT; ++kk) {
        float dl = 0.0f;
        if (kk <= Tb) {
            int rec = rec_s[kk];
            int d = rec & 3;
            if (d == 2) {                          // up: rows i < ih -> +RowTot
                int ih = (rec >> 2) & 0x1FF;
                if (tid < ih) { dl = RT - ww; ww = RT; cc = tid + 1; }
            } else if (d == 0) {                   // down: truncate prefix to jh
                int jh = (rec >> 11) & 0x1FF;
                if (cc > jh) { float wn = 2.0f * pk[kk] - RT; dl = wn - ww; ww = wn; cc = jh; }
            }
        }
        vals[1 + kk] = dl;
    }

    // reduce all TT+2 quantities: wave shuffle then cross-wave via LDS
    #pragma unroll
    for (int q = 0; q < TT + 2; ++q)
        for (int off = 32; off; off >>= 1)
            vals[q] += __shfl_down(vals[q], off, 64);
    int lane = tid & 63, wv = tid >> 6;
    if (lane == 0) {
        #pragma unroll
        for (int q = 0; q < TT + 2; ++q) red[wv * (TT + 2) + q] = vals[q];
    }
    __syncthreads();
    if (tid < TT + 2)
        tot[tid] = red[tid] + red[(TT + 2) + tid] + red[2 * (TT + 2) + tid] + red[3 * (TT + 2) + tid];
    __syncthreads();
    if (tid < TT) {                                // 32-lane shuffle prefix-scan
        float x = tot[2 + tid];
        #pragma unroll
        for (int off = 1; off < TT; off <<= 1) {
            float y = __shfl_up(x, off, 64);
            if (tid >= off) x += y;
        }
        if (tid < Tb) out[t0 + tid] = (tot[1] + x) * (1.0f / tot[0]);
    }
}

extern "C" void kernel_launch(void* const* d_in, const int* in_sizes, int n_in,
                              void* d_out, int out_size, void* d_ws, size_t ws_size,
                              hipStream_t stream) {
    const float* h   = (const float*)d_in[0];
    const float* raw = (const float*)d_in[1];
    float* out = (float*)d_out;
    int M = in_sizes[0];            // 4000
    int G = (M + TT - 1) / TT;      // 125 chunks

    char* ws = (char*)d_ws;
    size_t off = 0;
    auto take = [&](size_t bytes) { size_t cur = off; off = (off + bytes + 255) & ~(size_t)255; return cur; };
    float*        PrefT  = (float*)(ws + take((size_t)(NN + 1) * NN * 4));
    float*        RowTot = (float*)(ws + take((size_t)NN * 4));
    int*          steps  = (int*)(ws + take((size_t)(M + 1) * 4));
    unsigned int* UDt    = (unsigned int*)(ws + take((size_t)G * NN * 4));

    kA<<<NN + G, 256, 0, stream>>>(h, raw, M, G, PrefT, RowTot, steps, UDt);
    kB<<<G, 256, 0, stream>>>(h, steps, UDt, PrefT, RowTot, out, M);
}